// Round 8
// baseline (526.848 us; speedup 1.0000x reference)
//
#include <hip/hip_runtime.h>

#define HW 65536
#define NOUT 81     // 9 mask + 4*18 off
#define NFEAT 192   // 144 patch + 48 passthrough
#define WROW 84     // padded weight row stride (float4-aligned 21-slices)

typedef unsigned short ushort_t;

__device__ __forceinline__ float bf2f(ushort_t u) {
    union { unsigned int i; float f; } v; v.i = ((unsigned int)u) << 16; return v.f;
}
__device__ __forceinline__ ushort_t f2bf(float f) {
    union { float f; unsigned int i; } v; v.f = f;
    unsigned int r = v.i + 0x7FFF + ((v.i >> 16) & 1);   // RNE
    return (ushort_t)(r >> 16);
}

// ---------------------------------------------------------------------------
// Setup: collapse (conv3x3 -> 1x1) into a single 192->81 linear map.
// Writes WtP padded to (192,84); pad entries zeroed. bias folded (+base pts).
// ---------------------------------------------------------------------------
__global__ __launch_bounds__(256) void setup_weights(
    const float* __restrict__ off_pconv_w,  // (4,16,16,3,3)
    const float* __restrict__ off_w,        // (4,18,64)
    const float* __restrict__ off_b,        // (4,18)
    const float* __restrict__ mask_pconv_w, // (16,16,3,3)
    const float* __restrict__ mask_w,       // (9,64)
    const float* __restrict__ mask_b,       // (9,)
    float* __restrict__ WtP,                // (192,84)
    float* __restrict__ biasP)              // (81,)
{
    int id = blockIdx.x * 256 + threadIdx.x;
    const float PTS[18] = {-1,-1, -1,0, -1,1, 0,-1, 0,0, 0,1, 1,-1, 1,0, 1,1};
    if (id < NFEAT * WROW) {
        int f = id / WROW;
        int o = id % WROW;
        float v = 0.f;
        if (o < NOUT) {
            if (f < 144) {
                int p = f >> 4, c = f & 15;
                float s = 0.f;
                if (o < 9) {
                    for (int cm = 0; cm < 16; ++cm)
                        s += mask_w[o * 64 + cm] * mask_pconv_w[(cm * 16 + c) * 9 + p];
                } else {
                    int oo = o - 9, i = oo / 18, j = oo % 18;
                    for (int cm = 0; cm < 16; ++cm)
                        s += off_w[(i * 18 + j) * 64 + cm] * off_pconv_w[((i * 16 + cm) * 16 + c) * 9 + p];
                }
                v = s;
            } else {
                int c = f - 144;
                if (o < 9) v = mask_w[o * 64 + 16 + c];
                else { int oo = o - 9, i = oo / 18, j = oo % 18; v = off_w[(i * 18 + j) * 64 + 16 + c]; }
            }
        }
        WtP[id] = v;
    } else if (id < NFEAT * WROW + NOUT) {
        int o = id - NFEAT * WROW;
        float v;
        if (o < 9) v = mask_b[o];
        else {
            int oo = o - 9, i = oo / 18, j = oo % 18;
            v = off_b[i * 18 + j] + PTS[j] * (float)(2 * i + 1);
        }
        biasP[o] = v;
    }
}

// ---------------------------------------------------------------------------
// Transpose y (4,64,HW) f32 -> Tb[(t*8+z)][pix][16c] bf16 (32B rows).
// ---------------------------------------------------------------------------
__global__ __launch_bounds__(256) void transpose_y_b(
    const float* __restrict__ y, ushort_t* __restrict__ Tb)
{
    int bid = blockIdx.x;            // 2048
    int z = bid & 7, pr = bid >> 3;
    int pix = pr * 256 + threadIdx.x;
    int xb = z >> 2, i = z & 3;

    const float* p1 = y + (size_t)(xb * 64 + i * 16) * HW + pix;
    const float* p2 = y + (size_t)((xb + 2) * 64 + i * 16) * HW + pix;

    ushort_t v[16];
#pragma unroll
    for (int c = 0; c < 16; ++c) v[c] = f2bf(p1[(size_t)c * HW]);
    uint4* dst = (uint4*)(Tb + ((size_t)z * HW + pix) * 16);
    dst[0] = *(const uint4*)&v[0];
    dst[1] = *(const uint4*)&v[8];

#pragma unroll
    for (int c = 0; c < 16; ++c) v[c] = f2bf(p2[(size_t)c * HW]);
    dst = (uint4*)(Tb + ((size_t)(8 + z) * HW + pix) * 16);
    dst[0] = *(const uint4*)&v[0];
    dst[1] = *(const uint4*)&v[8];
}

#define FMA21(XV, WR) do {                                            \
    float4 w0_ = *(const float4*)(WR);                                \
    float4 w1_ = *(const float4*)((WR) + 4);                          \
    float4 w2_ = *(const float4*)((WR) + 8);                          \
    float4 w3_ = *(const float4*)((WR) + 12);                         \
    float4 w4_ = *(const float4*)((WR) + 16);                         \
    float  w20_ = (WR)[20];                                           \
    acc[0]  = fmaf(XV, w0_.x, acc[0]);  acc[1]  = fmaf(XV, w0_.y, acc[1]);  \
    acc[2]  = fmaf(XV, w0_.z, acc[2]);  acc[3]  = fmaf(XV, w0_.w, acc[3]);  \
    acc[4]  = fmaf(XV, w1_.x, acc[4]);  acc[5]  = fmaf(XV, w1_.y, acc[5]);  \
    acc[6]  = fmaf(XV, w1_.z, acc[6]);  acc[7]  = fmaf(XV, w1_.w, acc[7]);  \
    acc[8]  = fmaf(XV, w2_.x, acc[8]);  acc[9]  = fmaf(XV, w2_.y, acc[9]);  \
    acc[10] = fmaf(XV, w2_.z, acc[10]); acc[11] = fmaf(XV, w2_.w, acc[11]); \
    acc[12] = fmaf(XV, w3_.x, acc[12]); acc[13] = fmaf(XV, w3_.y, acc[13]); \
    acc[14] = fmaf(XV, w3_.z, acc[14]); acc[15] = fmaf(XV, w3_.w, acc[15]); \
    acc[16] = fmaf(XV, w4_.x, acc[16]); acc[17] = fmaf(XV, w4_.y, acc[17]); \
    acc[18] = fmaf(XV, w4_.z, acc[18]); acc[19] = fmaf(XV, w4_.w, acc[19]); \
    acc[20] = fmaf(XV, w20_, acc[20]);                                \
} while (0)

// ---------------------------------------------------------------------------
// FUSED kernel: block = 64 pixels x 4 lanes (c4).
// Phase 1: each thread computes 21 conv outputs (base c4*20; 1-col overlap
//          keeps lanes uniform; duplicates compute identical values) for its
//          pixel -> LDS tile S[64][81].
// Phase 2: warp_b structure: thread=(pixel,c4) handles 4 channels; quad lanes
//          share each 32B bf16 T-row; loops g(4) x k(9) x t(2).
// No off/mask workspace round-trip; conv FMA waves overlap gather waves.
// ---------------------------------------------------------------------------
__global__ __launch_bounds__(256) void fused_conv_warp(
    const float* __restrict__ x,      // (2,64,HW)
    const float* __restrict__ WtP,    // (192,84)
    const float* __restrict__ biasP,  // (81,)
    const ushort_t* __restrict__ Tb,  // (16,HW,16) bf16
    float* __restrict__ out)          // (4,64,9,HW)
{
    __shared__ float S[64 * NOUT];    // 20.7 KB
    int tid = threadIdx.x;
    int px = tid >> 2, c4 = tid & 3;
    int bid = blockIdx.x;             // 2048
    int b = bid >> 10;
    int pix = (bid & 1023) * 64 + px;
    int h = pix >> 8, w = pix & 255;
    int ob0 = c4 * 20;

    // ---- phase 1: conv (f32, same accumulation order as reference) ----
    float acc[21];
#pragma unroll
    for (int j = 0; j < 21; ++j) acc[j] = biasP[ob0 + j];

    const float* xb = x + (size_t)b * 64 * HW;

#pragma unroll 1
    for (int p = 0; p < 9; ++p) {
        int hh = h + p / 3 - 1;
        int ww = w + p % 3 - 1;
        bool valid = ((unsigned)hh < 256u) && ((unsigned)ww < 256u);
        int poff = hh * 256 + ww;
#pragma unroll 1
        for (int c = 0; c < 16; ++c) {
            float xv = valid ? xb[c * HW + poff] : 0.f;
            const float* wr = WtP + (p * 16 + c) * WROW + ob0;
            FMA21(xv, wr);
        }
    }
#pragma unroll 1
    for (int c = 0; c < 48; ++c) {
        float xv = xb[(16 + c) * HW + pix];
        const float* wr = WtP + (144 + c) * WROW + ob0;
        FMA21(xv, wr);
    }

    int sb = px * NOUT;
#pragma unroll
    for (int j = 0; j < 21; ++j) S[sb + ob0 + j] = acc[j];
    __syncthreads();

    // ---- phase 2: bilinear warp * mask, 4 channels per thread ----
    int sec = c4 * 4;
#pragma unroll 1
    for (int g = 0; g < 4; ++g) {
        const ushort_t* T0 = Tb + (size_t)(b * 4 + g) * HW * 16;
        const ushort_t* T1 = T0 + (size_t)8 * HW * 16;
        float* o0 = out + ((size_t)(b * 64 + g * 16 + c4 * 4)) * 9 * HW + pix;
        float* o1 = o0 + (size_t)128 * 9 * HW;

#pragma unroll 1
        for (int k = 0; k < 9; ++k) {
            float m  = S[sb + k];
            float ox = S[sb + 9 + g * 18 + 2 * k];
            float oy = S[sb + 10 + g * 18 + 2 * k];

            float pxf = fminf(fmaxf((float)w + ox, 0.f), 255.f);
            float pyf = fminf(fmaxf((float)h + oy, 0.f), 255.f);
            float x0f = floorf(pxf), y0f = floorf(pyf);
            float wx = pxf - x0f, wy = pyf - y0f;
            int x0 = (int)x0f, y0 = (int)y0f;
            int x1 = min(x0 + 1, 255), y1 = min(y0 + 1, 255);

            float w00 = (1.f - wx) * (1.f - wy) * m;
            float w01 = wx * (1.f - wy) * m;
            float w10 = (1.f - wx) * wy * m;
            float w11 = wx * wy * m;

            size_t r00 = (size_t)(y0 * 256 + x0) * 16 + sec;
            size_t r01 = (size_t)(y0 * 256 + x1) * 16 + sec;
            size_t r10 = (size_t)(y1 * 256 + x0) * 16 + sec;
            size_t r11 = (size_t)(y1 * 256 + x1) * 16 + sec;

            // tensor t=0
            {
                ushort4 va = *(const ushort4*)(T0 + r00);
                ushort4 vb = *(const ushort4*)(T0 + r01);
                ushort4 vc = *(const ushort4*)(T0 + r10);
                ushort4 vd = *(const ushort4*)(T0 + r11);
                float a0 = w00 * bf2f(va.x), a1 = w00 * bf2f(va.y);
                float a2 = w00 * bf2f(va.z), a3 = w00 * bf2f(va.w);
                a0 = fmaf(w01, bf2f(vb.x), a0); a1 = fmaf(w01, bf2f(vb.y), a1);
                a2 = fmaf(w01, bf2f(vb.z), a2); a3 = fmaf(w01, bf2f(vb.w), a3);
                a0 = fmaf(w10, bf2f(vc.x), a0); a1 = fmaf(w10, bf2f(vc.y), a1);
                a2 = fmaf(w10, bf2f(vc.z), a2); a3 = fmaf(w10, bf2f(vc.w), a3);
                a0 = fmaf(w11, bf2f(vd.x), a0); a1 = fmaf(w11, bf2f(vd.y), a1);
                a2 = fmaf(w11, bf2f(vd.z), a2); a3 = fmaf(w11, bf2f(vd.w), a3);
                float* ob = o0 + (size_t)k * HW;
                ob[0]               = a0;
                ob[(size_t)9 * HW]  = a1;
                ob[(size_t)18 * HW] = a2;
                ob[(size_t)27 * HW] = a3;
            }
            // tensor t=1
            {
                ushort4 va = *(const ushort4*)(T1 + r00);
                ushort4 vb = *(const ushort4*)(T1 + r01);
                ushort4 vc = *(const ushort4*)(T1 + r10);
                ushort4 vd = *(const ushort4*)(T1 + r11);
                float a0 = w00 * bf2f(va.x), a1 = w00 * bf2f(va.y);
                float a2 = w00 * bf2f(va.z), a3 = w00 * bf2f(va.w);
                a0 = fmaf(w01, bf2f(vb.x), a0); a1 = fmaf(w01, bf2f(vb.y), a1);
                a2 = fmaf(w01, bf2f(vb.z), a2); a3 = fmaf(w01, bf2f(vb.w), a3);
                a0 = fmaf(w10, bf2f(vc.x), a0); a1 = fmaf(w10, bf2f(vc.y), a1);
                a2 = fmaf(w10, bf2f(vc.z), a2); a3 = fmaf(w10, bf2f(vc.w), a3);
                a0 = fmaf(w11, bf2f(vd.x), a0); a1 = fmaf(w11, bf2f(vd.y), a1);
                a2 = fmaf(w11, bf2f(vd.z), a2); a3 = fmaf(w11, bf2f(vd.w), a3);
                float* ob = o1 + (size_t)k * HW;
                ob[0]               = a0;
                ob[(size_t)9 * HW]  = a1;
                ob[(size_t)18 * HW] = a2;
                ob[(size_t)27 * HW] = a3;
            }
        }
    }
}

// ---------------------------------------------------------------------------
// Fallback path (round-2 style, f32 y, off/mask workspace) if ws too small.
// ---------------------------------------------------------------------------
__global__ __launch_bounds__(512) void conv_offsets_lds(
    const float* __restrict__ x, const float* __restrict__ WtP,
    const float* __restrict__ biasP,
    float* __restrict__ mask_ws, float* __restrict__ off_ws)
{
    __shared__ float wl[NFEAT * WROW + NOUT];
    int tid = threadIdx.x;
    for (int idx = tid; idx < NFEAT * WROW; idx += 512) wl[idx] = WtP[idx];
    if (tid < NOUT) wl[NFEAT * WROW + tid] = biasP[tid];
    __syncthreads();

    int gid = blockIdx.x * 512 + tid;
    int b = gid >> 16;
    int pix = gid & 65535;
    int h = pix >> 8, w = pix & 255;

    float acc[NOUT];
#pragma unroll
    for (int o = 0; o < NOUT; ++o) acc[o] = wl[NFEAT * WROW + o];

    const float* xb = x + (size_t)b * 64 * HW;
    for (int p = 0; p < 9; ++p) {
        int hh = h + p / 3 - 1;
        int ww = w + p % 3 - 1;
        bool valid = ((unsigned)hh < 256u) && ((unsigned)ww < 256u);
        int poff = hh * 256 + ww;
        for (int c = 0; c < 16; ++c) {
            float xv = valid ? xb[c * HW + poff] : 0.f;
            const float* wr = &wl[(p * 16 + c) * WROW];
#pragma unroll
            for (int o = 0; o < NOUT; ++o) acc[o] = fmaf(xv, wr[o], acc[o]);
        }
    }
    for (int c = 0; c < 48; ++c) {
        float xv = xb[(16 + c) * HW + pix];
        const float* wr = &wl[(144 + c) * WROW];
#pragma unroll
        for (int o = 0; o < NOUT; ++o) acc[o] = fmaf(xv, wr[o], acc[o]);
    }
#pragma unroll
    for (int k = 0; k < 9; ++k) mask_ws[(b * 9 + k) * HW + pix] = acc[k];
#pragma unroll
    for (int t = 0; t < 72; ++t) off_ws[(b * 72 + t) * HW + pix] = acc[9 + t];
}

__global__ __launch_bounds__(256) void warp_apply(
    const float* __restrict__ y,
    const float* __restrict__ mask_ws,
    const float* __restrict__ off_ws,
    float* __restrict__ out)
{
    int w = threadIdx.x;
    int h = blockIdx.x;
    int k = blockIdx.y;
    int z = blockIdx.z;
    int xb = z >> 2, i = z & 3;
    int pix = h * 256 + w;

    float ox = off_ws[(size_t)(z * 18 + 2 * k) * HW + pix];
    float oy = off_ws[(size_t)(z * 18 + 2 * k + 1) * HW + pix];
    float m  = mask_ws[(size_t)(xb * 9 + k) * HW + pix];

    float px = fminf(fmaxf((float)w + ox, 0.f), 255.f);
    float py = fminf(fmaxf((float)h + oy, 0.f), 255.f);
    float x0f = floorf(px), y0f = floorf(py);
    float wx = px - x0f, wy = py - y0f;
    int x0 = (int)x0f, y0 = (int)y0f;
    int x1 = min(x0 + 1, 255), y1 = min(y0 + 1, 255);

    float w00 = (1.f - wx) * (1.f - wy) * m;
    float w01 = wx * (1.f - wy) * m;
    float w10 = (1.f - wx) * wy * m;
    float w11 = wx * wy * m;

    int o00 = y0 * 256 + x0, o01 = y0 * 256 + x1;
    int o10 = y1 * 256 + x0, o11 = y1 * 256 + x1;

    const float* p1 = y + (size_t)(xb * 64 + i * 16) * HW;
    const float* p2 = y + (size_t)((xb + 2) * 64 + i * 16) * HW;
    float* out1 = out + ((size_t)(xb * 64 + i * 16) * 9 + k) * HW + pix;
    float* out2 = out + ((size_t)((xb + 2) * 64 + i * 16) * 9 + k) * HW + pix;

#pragma unroll
    for (int c = 0; c < 16; ++c) {
        const float* q = p1 + (size_t)c * HW;
        float v = w00 * q[o00] + w01 * q[o01] + w10 * q[o10] + w11 * q[o11];
        out1[(size_t)c * 9 * HW] = v;
        q = p2 + (size_t)c * HW;
        v = w00 * q[o00] + w01 * q[o01] + w10 * q[o10] + w11 * q[o11];
        out2[(size_t)c * 9 * HW] = v;
    }
}

// ---------------------------------------------------------------------------
extern "C" void kernel_launch(void* const* d_in, const int* in_sizes, int n_in,
                              void* d_out, int out_size, void* d_ws, size_t ws_size,
                              hipStream_t stream) {
    const float* x            = (const float*)d_in[0];
    const float* y            = (const float*)d_in[1];
    const float* off_pconv_w  = (const float*)d_in[2];
    const float* off_w        = (const float*)d_in[3];
    const float* off_b        = (const float*)d_in[4];
    const float* mask_pconv_w = (const float*)d_in[5];
    const float* mask_w       = (const float*)d_in[6];
    const float* mask_b       = (const float*)d_in[7];
    float* out = (float*)d_out;

    // fused ws layout: [WtP 192*84 f32 + biasP: ~65KB] [Tb bf16: 33.5MB]
    float* WtP     = (float*)d_ws;
    float* biasP   = WtP + NFEAT * WROW;
    ushort_t* Tb   = (ushort_t*)((char*)d_ws + 131072);
    size_t need_fused = 131072 + (size_t)16 * HW * 16 * 2;

    setup_weights<<<64, 256, 0, stream>>>(off_pconv_w, off_w, off_b,
                                          mask_pconv_w, mask_w, mask_b, WtP, biasP);

    if (ws_size >= need_fused) {
        transpose_y_b<<<2048, 256, 0, stream>>>(y, Tb);
        fused_conv_warp<<<2048, 256, 0, stream>>>(x, WtP, biasP, Tb, out);
    } else {
        // fallback: f32 off/mask workspace path
        float* mask_ws = (float*)((char*)d_ws + 131072);
        float* off_ws  = mask_ws + (size_t)2 * 9 * HW;
        conv_offsets_lds<<<256, 512, 0, stream>>>(x, WtP, biasP, mask_ws, off_ws);
        dim3 g2(256, 9, 8);
        warp_apply<<<g2, 256, 0, stream>>>(y, mask_ws, off_ws, out);
    }
}

// Round 9
// 446.866 us; speedup vs baseline: 1.1790x; 1.1790x over previous
//
#include <hip/hip_runtime.h>

#define HW 65536
#define NOUT 81     // 9 mask + 4*18 off
#define NFEAT 192   // 144 patch + 48 passthrough
#define WROW 84     // padded weight row stride
#define OROW 96     // per-pixel off/mask row stride (floats)

typedef unsigned short ushort_t;

__device__ __forceinline__ float bf2f(ushort_t u) {
    union { unsigned int i; float f; } v; v.i = ((unsigned int)u) << 16; return v.f;
}
__device__ __forceinline__ ushort_t f2bf(float f) {
    union { float f; unsigned int i; } v; v.f = f;
    unsigned int r = v.i + 0x7FFF + ((v.i >> 16) & 1);   // RNE
    return (ushort_t)(r >> 16);
}

// ---------------------------------------------------------------------------
// Setup: collapse (conv3x3 -> 1x1) into a single 192->81 linear map, padded.
// ---------------------------------------------------------------------------
__global__ __launch_bounds__(256) void setup_weights(
    const float* __restrict__ off_pconv_w,  // (4,16,16,3,3)
    const float* __restrict__ off_w,        // (4,18,64)
    const float* __restrict__ off_b,        // (4,18)
    const float* __restrict__ mask_pconv_w, // (16,16,3,3)
    const float* __restrict__ mask_w,       // (9,64)
    const float* __restrict__ mask_b,       // (9,)
    float* __restrict__ WtP,                // (192,84)
    float* __restrict__ biasP)              // (81,)
{
    int id = blockIdx.x * 256 + threadIdx.x;
    const float PTS[18] = {-1,-1, -1,0, -1,1, 0,-1, 0,0, 0,1, 1,-1, 1,0, 1,1};
    if (id < NFEAT * WROW) {
        int f = id / WROW;
        int o = id % WROW;
        float v = 0.f;
        if (o < NOUT) {
            if (f < 144) {
                int p = f >> 4, c = f & 15;
                float s = 0.f;
                if (o < 9) {
                    for (int cm = 0; cm < 16; ++cm)
                        s += mask_w[o * 64 + cm] * mask_pconv_w[(cm * 16 + c) * 9 + p];
                } else {
                    int oo = o - 9, i = oo / 18, j = oo % 18;
                    for (int cm = 0; cm < 16; ++cm)
                        s += off_w[(i * 18 + j) * 64 + cm] * off_pconv_w[((i * 16 + cm) * 16 + c) * 9 + p];
                }
                v = s;
            } else {
                int c = f - 144;
                if (o < 9) v = mask_w[o * 64 + 16 + c];
                else { int oo = o - 9, i = oo / 18, j = oo % 18; v = off_w[(i * 18 + j) * 64 + 16 + c]; }
            }
        }
        WtP[id] = v;
    } else if (id < NFEAT * WROW + NOUT) {
        int o = id - NFEAT * WROW;
        float v;
        if (o < 9) v = mask_b[o];
        else {
            int oo = o - 9, i = oo / 18, j = oo % 18;
            v = off_b[i * 18 + j] + PTS[j] * (float)(2 * i + 1);
        }
        biasP[o] = v;
    }
}

// 84 FMAs: 21-output weight slice applied to 4 pixels' x values.
#define FMA21X4(X0, X1, X2, X3, WR) do {                                   \
    _Pragma("unroll")                                                      \
    for (int j5 = 0; j5 < 5; ++j5) {                                       \
        float4 w4 = *(const float4*)((WR) + 4 * j5);                       \
        acc0[4*j5+0] = fmaf(X0, w4.x, acc0[4*j5+0]);                       \
        acc0[4*j5+1] = fmaf(X0, w4.y, acc0[4*j5+1]);                       \
        acc0[4*j5+2] = fmaf(X0, w4.z, acc0[4*j5+2]);                       \
        acc0[4*j5+3] = fmaf(X0, w4.w, acc0[4*j5+3]);                       \
        acc1[4*j5+0] = fmaf(X1, w4.x, acc1[4*j5+0]);                       \
        acc1[4*j5+1] = fmaf(X1, w4.y, acc1[4*j5+1]);                       \
        acc1[4*j5+2] = fmaf(X1, w4.z, acc1[4*j5+2]);                       \
        acc1[4*j5+3] = fmaf(X1, w4.w, acc1[4*j5+3]);                       \
        acc2[4*j5+0] = fmaf(X2, w4.x, acc2[4*j5+0]);                       \
        acc2[4*j5+1] = fmaf(X2, w4.y, acc2[4*j5+1]);                       \
        acc2[4*j5+2] = fmaf(X2, w4.z, acc2[4*j5+2]);                       \
        acc2[4*j5+3] = fmaf(X2, w4.w, acc2[4*j5+3]);                       \
        acc3[4*j5+0] = fmaf(X3, w4.x, acc3[4*j5+0]);                       \
        acc3[4*j5+1] = fmaf(X3, w4.y, acc3[4*j5+1]);                       \
        acc3[4*j5+2] = fmaf(X3, w4.z, acc3[4*j5+2]);                       \
        acc3[4*j5+3] = fmaf(X3, w4.w, acc3[4*j5+3]);                       \
    }                                                                      \
    {                                                                      \
        float w20 = (WR)[20];                                              \
        acc0[20] = fmaf(X0, w20, acc0[20]);                                \
        acc1[20] = fmaf(X1, w20, acc1[20]);                                \
        acc2[20] = fmaf(X2, w20, acc2[20]);                                \
        acc3[20] = fmaf(X3, w20, acc3[20]);                                \
    }                                                                      \
} while (0)

// ---------------------------------------------------------------------------
// Conv kernel: thread = (4-pixel group, 21-output slice). Weights in LDS,
// read once per 4 pixels (4x amortization); quad slices hit disjoint banks,
// broadcast across pixel-quads is free. Output: per-pixel rows offm[b][pix][96]
// (mask 0..8, off 9..80), float4 stores.
// ---------------------------------------------------------------------------
__global__ __launch_bounds__(256, 2) void conv_px4(
    const float* __restrict__ x,     // (2,64,HW)
    const float* __restrict__ WtP,   // (192,84)
    const float* __restrict__ biasP, // (81,)
    float* __restrict__ offm)        // (2,HW,96)
{
    __shared__ float wl[NFEAT * WROW];    // 64.5 KB
    int tid = threadIdx.x;
    {
        const float4* src = (const float4*)WtP;
        float4* dst = (float4*)wl;
        for (int idx = tid; idx < NFEAT * WROW / 4; idx += 256) dst[idx] = src[idx];
    }
    __syncthreads();

    int c4 = tid & 3, grp = tid >> 2;
    int bid = blockIdx.x;            // 512
    int b = bid >> 8, h = bid & 255;
    int wbase = grp * 4;
    int pix0 = h * 256 + wbase;
    int ob0 = c4 * 20;

    float acc0[21], acc1[21], acc2[21], acc3[21];
#pragma unroll
    for (int j = 0; j < 21; ++j) {
        float bj = biasP[ob0 + j];
        acc0[j] = bj; acc1[j] = bj; acc2[j] = bj; acc3[j] = bj;
    }

    const float* xb = x + (size_t)b * 64 * HW;

    // 3x3 patch over channels 0..15: row-window of 6 values serves all 3 dw.
#pragma unroll 1
    for (int r = 0; r < 3; ++r) {
        int hh = h + r - 1;
        bool vrow = ((unsigned)hh < 256u);
        int rbase = hh * 256 + wbase;
#pragma unroll 1
        for (int c = 0; c < 16; ++c) {
            const float* xr = xb + c * HW + rbase;
            float4 x4 = vrow ? *(const float4*)xr : make_float4(0.f, 0.f, 0.f, 0.f);
            float xm1 = (vrow && wbase > 0)     ? xr[-1] : 0.f;
            float xp4 = (vrow && wbase + 4 < 256) ? xr[4]  : 0.f;
            const float* wr0 = wl + ((r * 3 + 0) * 16 + c) * WROW + ob0;
            const float* wr1 = wl + ((r * 3 + 1) * 16 + c) * WROW + ob0;
            const float* wr2 = wl + ((r * 3 + 2) * 16 + c) * WROW + ob0;
            FMA21X4(xm1, x4.x, x4.y, x4.z, wr0);   // dw = -1
            FMA21X4(x4.x, x4.y, x4.z, x4.w, wr1);  // dw = 0
            FMA21X4(x4.y, x4.z, x4.w, xp4, wr2);   // dw = +1
        }
    }
    // passthrough channels 16..63
#pragma unroll 1
    for (int c = 0; c < 48; ++c) {
        float4 x4 = *(const float4*)(xb + (16 + c) * HW + pix0);
        const float* wr = wl + (144 + c) * WROW + ob0;
        FMA21X4(x4.x, x4.y, x4.z, x4.w, wr);
    }

    // store per-pixel rows (slices overlap at 20/40/60 with identical values)
    float* base = offm + ((size_t)b * HW + pix0) * OROW + ob0;
#pragma unroll
    for (int j5 = 0; j5 < 5; ++j5) {
        *(float4*)(base + 0 * OROW + 4 * j5) = make_float4(acc0[4*j5], acc0[4*j5+1], acc0[4*j5+2], acc0[4*j5+3]);
        *(float4*)(base + 1 * OROW + 4 * j5) = make_float4(acc1[4*j5], acc1[4*j5+1], acc1[4*j5+2], acc1[4*j5+3]);
        *(float4*)(base + 2 * OROW + 4 * j5) = make_float4(acc2[4*j5], acc2[4*j5+1], acc2[4*j5+2], acc2[4*j5+3]);
        *(float4*)(base + 3 * OROW + 4 * j5) = make_float4(acc3[4*j5], acc3[4*j5+1], acc3[4*j5+2], acc3[4*j5+3]);
    }
    base[0 * OROW + 20] = acc0[20];
    base[1 * OROW + 20] = acc1[20];
    base[2 * OROW + 20] = acc2[20];
    base[3 * OROW + 20] = acc3[20];
}

// ---------------------------------------------------------------------------
// Transpose y -> interleaved Tb[z][pix][2t*16c] bf16 (64B per pixel: both
// tensors' 16 channels share one cache line at identical gather coords).
// ---------------------------------------------------------------------------
__global__ __launch_bounds__(256) void transpose_y_i(
    const float* __restrict__ y, ushort_t* __restrict__ Tb)
{
    int bid = blockIdx.x;            // 2048
    int z = bid & 7, pr = bid >> 3;
    int pix = pr * 256 + threadIdx.x;
    int xb = z >> 2, i = z & 3;

    const float* p0 = y + (size_t)(xb * 64 + i * 16) * HW + pix;
    const float* p1 = y + (size_t)((xb + 2) * 64 + i * 16) * HW + pix;

    ushort_t v[32];
#pragma unroll
    for (int c = 0; c < 16; ++c) v[c]      = f2bf(p0[(size_t)c * HW]);
#pragma unroll
    for (int c = 0; c < 16; ++c) v[16 + c] = f2bf(p1[(size_t)c * HW]);

    uint4* dst = (uint4*)(Tb + ((size_t)z * HW + pix) * 32);
    dst[0] = *(const uint4*)&v[0];
    dst[1] = *(const uint4*)&v[8];
    dst[2] = *(const uint4*)&v[16];
    dst[3] = *(const uint4*)&v[24];
}

// ---------------------------------------------------------------------------
// Warp kernel: thread = (pixel, c4); quad lanes share each 64B Tb row; both
// tensors' gathers per corner hit the same line. off/mask read from the
// per-pixel offm row (broadcast within quad).
// ---------------------------------------------------------------------------
__global__ __launch_bounds__(256) void warp_apply_i(
    const ushort_t* __restrict__ Tb,   // (8,HW,32) bf16
    const float* __restrict__ offm,    // (2,HW,96)
    float* __restrict__ out)           // (4,64,9,HW)
{
    int bid = blockIdx.x;            // 8192
    int z  = bid & 7;
    int wc = (bid >> 3) & 3;
    int h  = bid >> 5;               // 0..255
    int c4 = threadIdx.x & 3;
    int pl = threadIdx.x >> 2;       // 0..63
    int w  = wc * 64 + pl;
    int pix = h * 256 + w;
    int xb = z >> 2, g = z & 3;

    const ushort_t* Tt = Tb + (size_t)z * HW * 32;
    const float* orow = offm + ((size_t)xb * HW + pix) * OROW;

    float* o0 = out + (size_t)(xb * 64 + g * 16 + c4 * 4) * 9 * HW + pix;
    float* o1 = o0 + (size_t)128 * 9 * HW;
    int sec = c4 * 4;

#pragma unroll 1
    for (int k = 0; k < 9; ++k) {
        float m  = orow[k];
        float ox = orow[9 + g * 18 + 2 * k];
        float oy = orow[10 + g * 18 + 2 * k];

        float pxf = fminf(fmaxf((float)w + ox, 0.f), 255.f);
        float pyf = fminf(fmaxf((float)h + oy, 0.f), 255.f);
        float x0f = floorf(pxf), y0f = floorf(pyf);
        float wx = pxf - x0f, wy = pyf - y0f;
        int x0 = (int)x0f, y0 = (int)y0f;
        int x1 = min(x0 + 1, 255), y1 = min(y0 + 1, 255);

        float w00 = (1.f - wx) * (1.f - wy) * m;
        float w01 = wx * (1.f - wy) * m;
        float w10 = (1.f - wx) * wy * m;
        float w11 = wx * wy * m;

        size_t r00 = (size_t)(y0 * 256 + x0) * 32 + sec;
        size_t r01 = (size_t)(y0 * 256 + x1) * 32 + sec;
        size_t r10 = (size_t)(y1 * 256 + x0) * 32 + sec;
        size_t r11 = (size_t)(y1 * 256 + x1) * 32 + sec;

        // issue all 8 gathers before use (t1 shares lines with t0)
        ushort4 a0 = *(const ushort4*)(Tt + r00);
        ushort4 b0 = *(const ushort4*)(Tt + r01);
        ushort4 c0 = *(const ushort4*)(Tt + r10);
        ushort4 d0 = *(const ushort4*)(Tt + r11);
        ushort4 a1 = *(const ushort4*)(Tt + r00 + 16);
        ushort4 b1 = *(const ushort4*)(Tt + r01 + 16);
        ushort4 c1 = *(const ushort4*)(Tt + r10 + 16);
        ushort4 d1 = *(const ushort4*)(Tt + r11 + 16);

        float s0 = w00 * bf2f(a0.x), s1 = w00 * bf2f(a0.y);
        float s2 = w00 * bf2f(a0.z), s3 = w00 * bf2f(a0.w);
        s0 = fmaf(w01, bf2f(b0.x), s0); s1 = fmaf(w01, bf2f(b0.y), s1);
        s2 = fmaf(w01, bf2f(b0.z), s2); s3 = fmaf(w01, bf2f(b0.w), s3);
        s0 = fmaf(w10, bf2f(c0.x), s0); s1 = fmaf(w10, bf2f(c0.y), s1);
        s2 = fmaf(w10, bf2f(c0.z), s2); s3 = fmaf(w10, bf2f(c0.w), s3);
        s0 = fmaf(w11, bf2f(d0.x), s0); s1 = fmaf(w11, bf2f(d0.y), s1);
        s2 = fmaf(w11, bf2f(d0.z), s2); s3 = fmaf(w11, bf2f(d0.w), s3);

        float t0v = w00 * bf2f(a1.x), t1v = w00 * bf2f(a1.y);
        float t2v = w00 * bf2f(a1.z), t3v = w00 * bf2f(a1.w);
        t0v = fmaf(w01, bf2f(b1.x), t0v); t1v = fmaf(w01, bf2f(b1.y), t1v);
        t2v = fmaf(w01, bf2f(b1.z), t2v); t3v = fmaf(w01, bf2f(b1.w), t3v);
        t0v = fmaf(w10, bf2f(c1.x), t0v); t1v = fmaf(w10, bf2f(c1.y), t1v);
        t2v = fmaf(w10, bf2f(c1.z), t2v); t3v = fmaf(w10, bf2f(c1.w), t3v);
        t0v = fmaf(w11, bf2f(d1.x), t0v); t1v = fmaf(w11, bf2f(d1.y), t1v);
        t2v = fmaf(w11, bf2f(d1.z), t2v); t3v = fmaf(w11, bf2f(d1.w), t3v);

        float* p0 = o0 + (size_t)k * HW;
        p0[0]               = s0;
        p0[(size_t)9 * HW]  = s1;
        p0[(size_t)18 * HW] = s2;
        p0[(size_t)27 * HW] = s3;
        float* p1 = o1 + (size_t)k * HW;
        p1[0]               = t0v;
        p1[(size_t)9 * HW]  = t1v;
        p1[(size_t)18 * HW] = t2v;
        p1[(size_t)27 * HW] = t3v;
    }
}

// ---------------------------------------------------------------------------
// Fallback path (no big workspace): LDS-weight conv to planes + direct warp.
// ---------------------------------------------------------------------------
__global__ __launch_bounds__(512) void conv_offsets_lds(
    const float* __restrict__ x, const float* __restrict__ WtP,
    const float* __restrict__ biasP,
    float* __restrict__ mask_ws, float* __restrict__ off_ws)
{
    __shared__ float wl[NFEAT * WROW + NOUT];
    int tid = threadIdx.x;
    for (int idx = tid; idx < NFEAT * WROW; idx += 512) wl[idx] = WtP[idx];
    if (tid < NOUT) wl[NFEAT * WROW + tid] = biasP[tid];
    __syncthreads();

    int gid = blockIdx.x * 512 + tid;
    int b = gid >> 16;
    int pix = gid & 65535;
    int h = pix >> 8, w = pix & 255;

    float acc[NOUT];
#pragma unroll
    for (int o = 0; o < NOUT; ++o) acc[o] = wl[NFEAT * WROW + o];

    const float* xb = x + (size_t)b * 64 * HW;
    for (int p = 0; p < 9; ++p) {
        int hh = h + p / 3 - 1;
        int ww = w + p % 3 - 1;
        bool valid = ((unsigned)hh < 256u) && ((unsigned)ww < 256u);
        int poff = hh * 256 + ww;
        for (int c = 0; c < 16; ++c) {
            float xv = valid ? xb[c * HW + poff] : 0.f;
            const float* wr = &wl[(p * 16 + c) * WROW];
#pragma unroll
            for (int o = 0; o < NOUT; ++o) acc[o] = fmaf(xv, wr[o], acc[o]);
        }
    }
    for (int c = 0; c < 48; ++c) {
        float xv = xb[(16 + c) * HW + pix];
        const float* wr = &wl[(144 + c) * WROW];
#pragma unroll
        for (int o = 0; o < NOUT; ++o) acc[o] = fmaf(xv, wr[o], acc[o]);
    }
#pragma unroll
    for (int k = 0; k < 9; ++k) mask_ws[(b * 9 + k) * HW + pix] = acc[k];
#pragma unroll
    for (int t = 0; t < 72; ++t) off_ws[(b * 72 + t) * HW + pix] = acc[9 + t];
}

__global__ __launch_bounds__(256) void warp_apply(
    const float* __restrict__ y,
    const float* __restrict__ mask_ws,
    const float* __restrict__ off_ws,
    float* __restrict__ out)
{
    int w = threadIdx.x;
    int h = blockIdx.x;
    int k = blockIdx.y;
    int z = blockIdx.z;
    int xb = z >> 2, i = z & 3;
    int pix = h * 256 + w;

    float ox = off_ws[(size_t)(z * 18 + 2 * k) * HW + pix];
    float oy = off_ws[(size_t)(z * 18 + 2 * k + 1) * HW + pix];
    float m  = mask_ws[(size_t)(xb * 9 + k) * HW + pix];

    float px = fminf(fmaxf((float)w + ox, 0.f), 255.f);
    float py = fminf(fmaxf((float)h + oy, 0.f), 255.f);
    float x0f = floorf(px), y0f = floorf(py);
    float wx = px - x0f, wy = py - y0f;
    int x0 = (int)x0f, y0 = (int)y0f;
    int x1 = min(x0 + 1, 255), y1 = min(y0 + 1, 255);

    float w00 = (1.f - wx) * (1.f - wy) * m;
    float w01 = wx * (1.f - wy) * m;
    float w10 = (1.f - wx) * wy * m;
    float w11 = wx * wy * m;

    int o00 = y0 * 256 + x0, o01 = y0 * 256 + x1;
    int o10 = y1 * 256 + x0, o11 = y1 * 256 + x1;

    const float* p1 = y + (size_t)(xb * 64 + i * 16) * HW;
    const float* p2 = y + (size_t)((xb + 2) * 64 + i * 16) * HW;
    float* out1 = out + ((size_t)(xb * 64 + i * 16) * 9 + k) * HW + pix;
    float* out2 = out + ((size_t)((xb + 2) * 64 + i * 16) * 9 + k) * HW + pix;

#pragma unroll
    for (int c = 0; c < 16; ++c) {
        const float* q = p1 + (size_t)c * HW;
        float v = w00 * q[o00] + w01 * q[o01] + w10 * q[o10] + w11 * q[o11];
        out1[(size_t)c * 9 * HW] = v;
        q = p2 + (size_t)c * HW;
        v = w00 * q[o00] + w01 * q[o01] + w10 * q[o10] + w11 * q[o11];
        out2[(size_t)c * 9 * HW] = v;
    }
}

// ---------------------------------------------------------------------------
extern "C" void kernel_launch(void* const* d_in, const int* in_sizes, int n_in,
                              void* d_out, int out_size, void* d_ws, size_t ws_size,
                              hipStream_t stream) {
    const float* x            = (const float*)d_in[0];
    const float* y            = (const float*)d_in[1];
    const float* off_pconv_w  = (const float*)d_in[2];
    const float* off_w        = (const float*)d_in[3];
    const float* off_b        = (const float*)d_in[4];
    const float* mask_pconv_w = (const float*)d_in[5];
    const float* mask_w       = (const float*)d_in[6];
    const float* mask_b       = (const float*)d_in[7];
    float* out = (float*)d_out;

    // ws: [WtP 192*84 f32 | biasP : 64KB+] [offm (2,HW,96) f32: 50.3MB]
    //     [Tb (8,HW,32) bf16: 33.6MB]   total ~84MB
    float* WtP     = (float*)d_ws;
    float* biasP   = WtP + NFEAT * WROW;
    float* offm    = (float*)((char*)d_ws + 65536);
    ushort_t* Tb   = (ushort_t*)((char*)offm + (size_t)2 * HW * OROW * 4);
    size_t need = 65536 + (size_t)2 * HW * OROW * 4 + (size_t)8 * HW * 32 * 2;

    setup_weights<<<64, 256, 0, stream>>>(off_pconv_w, off_w, off_b,
                                          mask_pconv_w, mask_w, mask_b, WtP, biasP);

    if (ws_size >= need) {
        conv_px4<<<512, 256, 0, stream>>>(x, WtP, biasP, offm);
        transpose_y_i<<<2048, 256, 0, stream>>>(y, Tb);
        warp_apply_i<<<8192, 256, 0, stream>>>(Tb, offm, out);
    } else {
        float* mask_ws = (float*)((char*)d_ws + 131072);
        float* off_ws  = mask_ws + (size_t)2 * 9 * HW;
        conv_offsets_lds<<<256, 512, 0, stream>>>(x, WtP, biasP, mask_ws, off_ws);
        dim3 g2(256, 9, 8);
        warp_apply<<<g2, 256, 0, stream>>>(y, mask_ws, off_ws, out);
    }
}